// Round 14
// baseline (226.878 us; speedup 1.0000x reference)
//
#include <hip/hip_runtime.h>
#include <stdint.h>

// Top-K (K=64) per row of [4096, 32768] f32, relu'd, scattered into zeros.
//
// Round-14: WAVE-OWNS-ROW, ZERO BARRIERS.
//   R13 closed the last block-structure lever (register depth: +1%). The
//   unexplained cost (R10: pure-read select ran ~150us vs ~81us read floor)
//   is the block-wide tail: every __syncthreads drains vmcnt(0) of all 32
//   outstanding NT stores x 4 waves, and resident blocks hit their tails in
//   lockstep (equal BW share) so tails don't overlap streaming.
//   This round removes ALL __syncthreads: each 64-lane wave independently
//   owns one row; capture, expansion, radix select, tie-break and scatter
//   are wave-local (LDS regions private per wave; within-wave LDS ordering
//   needs only lgkmcnt => __threadfence_block, no barrier). Waves
//   desynchronize; a wave's tail hides under other waves' streaming.
//  - Stream: 8-deep float4 loads + NT zero stores; per group (float4):
//    2 v_max + cmp + min + ds_write_b16 of the GROUP INDEX (uint16) to a
//    wave-private slot, count bump. Branchless, atomic-free.
//  - Tail (wave-local): re-read captured groups (16B, L2-hot), expand
//    elements >= FCUT into wave list via wave-scoped LDS atomicAdd; exact
//    4x8-bit radix over raw positive-float bits (wave hist + shfl scan,
//    selection broadcast via ballot+shfl); scatter <=64 winners; ties at
//    the exact 32-bit key lowest-index-first (matches jax.lax.top_k).
//  - Fallback (slot ovf / list ovf / M<64; P ~ 1e-4 per launch): exact
//    wave-local 4x8-bit radix over f2o keys from global re-reads, ordered
//    rank pass, explicit relu. Exact for ANY input.

#define LROW   32768
#define NT     256
#define NW     4                    // waves per block; block covers 4 rows
#define GPL    (LROW / 4 / 64)      // float4 groups per lane = 128
#define KSEL   64u
#define NSLOT  16                   // uint16 slots per lane (+1 trash)
#define CAPW   512u                 // wave candidate list capacity
#define FCUT   2.6f                 // candidate threshold (value space)

typedef float vf4 __attribute__((ext_vector_type(4)));

// float bits -> order-preserving uint (fallback only)
__device__ __forceinline__ uint32_t f2o(uint32_t b) {
    return b ^ (uint32_t)(((int32_t)b >> 31) | 0x80000000u);
}
__device__ __forceinline__ float o2f(uint32_t u) {
    uint32_t b = (u & 0x80000000u) ? (u ^ 0x80000000u) : ~u;
    return __uint_as_float(b);
}

// Wave-local: scan h256[255..0] from the top; find bucket b* with
// cum_before < need <= cum_before + h[b*]. Result broadcast to all lanes
// via ballot+shfl (no LDS, no barrier).
__device__ __forceinline__ void wave_scan_hist(const uint32_t* h256, uint32_t need,
                                               int lane, uint32_t& bsel,
                                               uint32_t& cumsel, uint32_t& cntsel)
{
    uint32_t cum = 0;
    bool done = false;
    #pragma unroll
    for (int base = 256; base > 0; base -= 64) {
        if (!done) {
            uint32_t hc = h256[base - 1 - lane];   // lane 0 = highest bucket
            uint32_t inc = hc;
            #pragma unroll
            for (int off = 1; off < 64; off <<= 1) {
                uint32_t t = __shfl_up(inc, off);
                if (lane >= off) inc += t;
            }
            uint32_t tot = __shfl(inc, 63);
            uint32_t pre = inc - hc;
            bool hit = (cum + pre < need) && (cum + pre + hc >= need);
            unsigned long long bal = __ballot(hit);
            if (bal != 0ull) {                     // exactly one lane hits
                int hl = (int)(__ffsll((long long)bal) - 1);
                bsel   = __shfl((uint32_t)(base - 1 - lane), hl);
                cumsel = __shfl(cum + pre, hl);
                cntsel = __shfl(hc, hl);
                done = true;
            }
            cum += tot;
        }
    }
}

__global__ __launch_bounds__(NT, 4) void topk_kernel(
    const float* __restrict__ x, float* __restrict__ out, int rows)
{
    __shared__ uint16_t slots[NW][(NSLOT + 1) * 64];  // 8.5 KiB: group idxs
    __shared__ uint2    wlist[NW][CAPW];              // 16 KiB: {key,pos}
    __shared__ uint32_t hist[NW][256];                // 4 KiB
    __shared__ uint32_t wcnt[NW];

    const int tid  = threadIdx.x;
    const int lane = tid & 63;
    const int wid  = tid >> 6;
    const int row  = blockIdx.x * NW + wid;
    if (row >= rows) return;                          // wave-uniform
    const size_t rowoff = (size_t)row * LROW;
    const float4* __restrict__ xin  = (const float4*)(x + rowoff);
    vf4*          __restrict__ xout = (vf4*)(out + rowoff);

    if (lane == 0) wcnt[wid] = 0u;

    // ---- Stream (wave-private): 8 loads | 8 NT zero-stores | 8 captures ----
    uint32_t c = 0;
    const vf4 z = (vf4)(0.0f);
    for (int i = 0; i < GPL; i += 8) {
        int p[8]; float4 v[8];
        #pragma unroll
        for (int b = 0; b < 8; ++b) p[b] = (i + b) * 64 + lane;
        #pragma unroll
        for (int b = 0; b < 8; ++b) v[b] = xin[p[b]];
        #pragma unroll
        for (int b = 0; b < 8; ++b)
            __builtin_nontemporal_store(z, &xout[p[b]]);
        #pragma unroll
        for (int b = 0; b < 8; ++b) {
            float m = fmaxf(fmaxf(v[b].x, v[b].y), fmaxf(v[b].z, v[b].w));
            uint32_t s = (c > (uint32_t)NSLOT) ? (uint32_t)NSLOT : c;
            slots[wid][s * 64 + lane] = (uint16_t)p[b];
            c += (m >= FCUT) ? 1u : 0u;
        }
    }

    // ---- Expansion (wave-local; lgkmcnt ordering only) ----
    bool lovf = (c > (uint32_t)NSLOT);
    uint32_t cc = lovf ? (uint32_t)NSLOT : c;
    __threadfence_block();                 // wcnt=0 + own slot writes ordered
    for (uint32_t s = 0; s < cc; ++s) {
        int p4 = (int)slots[wid][s * 64 + lane];
        float4 v = xin[p4];                // 16B gather, L2/L3-hot
        float fa[4] = {v.x, v.y, v.z, v.w};
        #pragma unroll
        for (int q = 0; q < 4; ++q) {
            if (fa[q] >= FCUT) {
                uint32_t idx = atomicAdd(&wcnt[wid], 1u);
                if (idx < CAPW)
                    wlist[wid][idx] = make_uint2(__float_as_uint(fa[q]),
                                                 (uint32_t)(p4 * 4 + q));
                else
                    lovf = true;
            }
        }
    }
    __threadfence_block();                 // list + counter visible wave-wide
    const bool     ovf = __any(lovf);
    const uint32_t M   = wcnt[wid];

    if (!ovf && M >= KSEL && M <= CAPW) {
        // ---- Exact 4x8-bit radix over M candidates (raw bits, all > 0) ----
        uint32_t need = KSEL, pref = 0, cnt = 0;
        #pragma unroll
        for (int L = 3; L >= 0; --L) {
            #pragma unroll
            for (int h = 0; h < 4; ++h) hist[wid][h * 64 + lane] = 0u;
            __threadfence_block();
            for (uint32_t i = lane; i < M; i += 64) {
                uint32_t u = wlist[wid][i].x;
                bool inb = (L == 3) || ((u >> ((L + 1) * 8)) == pref);
                if (inb) atomicAdd(&hist[wid][(u >> (L * 8)) & 0xFFu], 1u);
            }
            __threadfence_block();
            uint32_t b_, cum_, cnt_;
            wave_scan_hist(hist[wid], need, lane, b_, cum_, cnt_);
            pref = (pref << 8) | b_;
            need -= cum_;                  // 1..cnt_
            cnt = cnt_;
        }
        const uint32_t T32 = pref;         // exact 64th-largest key
        const uint32_t r   = need;         // #(==T32) to take, lowest idx first

        // ---- Scatter winners (wave-local) ----
        for (uint32_t i = lane; i < M; i += 64) {
            uint2 e = wlist[wid][i];
            if (e.x > T32) {
                out[rowoff + e.y] = __uint_as_float(e.x);   // >= 2.6 > 0
            } else if (e.x == T32) {
                bool take = (r == cnt);
                if (!take) {
                    uint32_t rank = 0;
                    for (uint32_t j2 = 0; j2 < M; ++j2) {
                        uint2 o2 = wlist[wid][j2];
                        rank += (o2.x == T32 && o2.y < e.y);
                    }
                    take = (rank < r);
                }
                if (take) out[rowoff + e.y] = __uint_as_float(e.x);
            }
        }
        return;
    }

    // ---- Fallback (wave-local, exact for ANY input; statistically never):
    //      4x8-bit radix over f2o keys re-read from global ----
    uint32_t need = KSEL, pref = 0, cnt = 0;
    #pragma unroll
    for (int L = 3; L >= 0; --L) {
        #pragma unroll
        for (int h = 0; h < 4; ++h) hist[wid][h * 64 + lane] = 0u;
        __threadfence_block();
        for (int g = 0; g < GPL; ++g) {
            float4 v = xin[g * 64 + lane];
            uint32_t u[4] = { f2o(__float_as_uint(v.x)), f2o(__float_as_uint(v.y)),
                              f2o(__float_as_uint(v.z)), f2o(__float_as_uint(v.w)) };
            #pragma unroll
            for (int q = 0; q < 4; ++q) {
                bool inb = (L == 3) || ((u[q] >> ((L + 1) * 8)) == pref);
                if (inb) atomicAdd(&hist[wid][(u[q] >> (L * 8)) & 0xFFu], 1u);
            }
        }
        __threadfence_block();
        uint32_t b_, cum_, cnt_;
        wave_scan_hist(hist[wid], need, lane, b_, cum_, cnt_);
        pref = (pref << 8) | b_;
        need -= cum_;
        cnt = cnt_;
    }
    const uint32_t T32f = pref;
    const uint32_t r2   = need;            // #(==T32f) to take, lowest idx first

    // Ordered rank among ==T32f: lane owns contiguous chunk (index order).
    const int cbase = lane * (LROW / 64);
    uint32_t ceq = 0;
    for (int j = 0; j < LROW / 64; ++j)
        ceq += (f2o(__float_as_uint(x[rowoff + cbase + j])) == T32f);
    uint32_t incp = ceq;
    #pragma unroll
    for (int off = 1; off < 64; off <<= 1) {
        uint32_t t = __shfl_up(incp, off);
        if (lane >= off) incp += t;
    }
    uint32_t rank = incp - ceq;            // exclusive prefix == global rank base
    for (int j = 0; j < LROW / 64; ++j) {
        uint32_t u = f2o(__float_as_uint(x[rowoff + cbase + j]));
        bool take = false;
        if (u > T32f) take = true;
        else if (u == T32f) { take = (rank < r2); rank++; }
        if (take) {
            float vv = o2f(u);
            if (vv > 0.f) out[rowoff + cbase + j] = vv;   // relu
        }
    }
}

extern "C" void kernel_launch(void* const* d_in, const int* in_sizes, int n_in,
                              void* d_out, int out_size, void* d_ws, size_t ws_size,
                              hipStream_t stream)
{
    const float* x = (const float*)d_in[0];
    float* out = (float*)d_out;
    int rows = in_sizes[0] / LROW;   // 4096

    int grid = (rows + NW - 1) / NW; // 1024 blocks x 4 waves = 4096 rows
    topk_kernel<<<grid, NT, 0, stream>>>(x, out, rows);
}